// Round 13
// baseline (1599.237 us; speedup 1.0000x reference)
//
#include <hip/hip_runtime.h>

// SimpleMTP: 3 sequential MTP heads on MI355X.
// f16 MFMA everywhere heavy; f32 residual/norms.
// Logits: PERSISTENT rect-resident GEMM. 120 blocks (15/XCD): XCD owns
//   3 bm (1.5MB A slice L2-resident for whole kernel); 15 blocks = 3bm x
//   5bn walk 25 rects in lockstep -> live working set 4.0MB = L2.
//   Fabric traffic 3.14GB -> 0.52GB. Inner loop = r9 4-phase schedule.
// Small GEMMs: 64x64, 3-buffer depth-2 prefetch.
// Wv/Wo fused into Wvo = Wo@Wv (precomputed per call).

#define NPOS   509
#define MROWS  2036
#define MPAD   2048
#define DMODEL 1024

typedef _Float16 f16;
typedef _Float16 f16x8 __attribute__((ext_vector_type(8)));
typedef _Float16 f16x4 __attribute__((ext_vector_type(4)));
typedef float    f32x4 __attribute__((ext_vector_type(4)));

#define MFMA16(a, b, c) __builtin_amdgcn_mfma_f32_16x16x32_f16(a, b, c, 0, 0, 0)
#define VM0   asm volatile("s_waitcnt vmcnt(0)" ::: "memory")
#define VM2   asm volatile("s_waitcnt vmcnt(2)" ::: "memory")
#define VM4   asm volatile("s_waitcnt vmcnt(4)" ::: "memory")
#define LGKM0 asm volatile("s_waitcnt lgkmcnt(0)" ::: "memory")
#define SCHED0 __builtin_amdgcn_sched_barrier(0)
#define BAR   asm volatile("s_barrier" ::: "memory")

__device__ __forceinline__ void gld_lds16(const void* g, void* l) {
  __builtin_amdgcn_global_load_lds(
      (const __attribute__((address_space(1))) void*)g,
      (__attribute__((address_space(3))) void*)l, 16, 0, 0);
}

// ---------------- f32 -> f16 convert: embed ----------------
__global__ __launch_bounds__(256) void conv_f32_f16(const float* __restrict__ src,
                                                    f16* __restrict__ dst, long n) {
  long i = ((long)blockIdx.x * 256 + threadIdx.x) * 8;
  if (i + 8 <= n) {
    float4 a = *(const float4*)(src + i);
    float4 b = *(const float4*)(src + i + 4);
    f16x8 o = {(f16)a.x, (f16)a.y, (f16)a.z, (f16)a.w,
               (f16)b.x, (f16)b.y, (f16)b.z, (f16)b.w};
    *(f16x8*)(dst + i) = o;
  }
}

// ---------------- batched weight conversion (12 tensors) ----------------
struct ConvArgs { const float* s[12]; f16* d[12]; long n[12]; };
__global__ __launch_bounds__(256) void conv_many(ConvArgs a) {
  int t = blockIdx.y;
  long i = ((long)blockIdx.x * 256 + threadIdx.x) * 8;
  if (i + 8 <= a.n[t]) {
    const float* src = a.s[t];
    float4 x = *(const float4*)(src + i);
    float4 y = *(const float4*)(src + i + 4);
    f16x8 o = {(f16)x.x, (f16)x.y, (f16)x.z, (f16)x.w,
               (f16)y.x, (f16)y.y, (f16)y.z, (f16)y.w};
    *(f16x8*)(a.d[t] + i) = o;
  }
}

// ---------------- batched 1024x1024 transpose f32->f16 (Wv -> WvT) ----------------
struct TpArgs { const float* s[3]; f16* d[3]; };
__global__ __launch_bounds__(256) void transpose3(TpArgs a) {
  __shared__ float t[32][33];
  int h = blockIdx.z;
  int bx = blockIdx.x * 32, by = blockIdx.y * 32;
  int tx = threadIdx.x & 31, ty = threadIdx.x >> 5;
  const float* src = a.s[h];
  f16* dst = a.d[h];
  #pragma unroll
  for (int r = 0; r < 32; r += 8)
    t[ty + r][tx] = src[(long)(by + ty + r) * 1024 + bx + tx];
  __syncthreads();
  #pragma unroll
  for (int r = 0; r < 32; r += 8)
    dst[(long)(bx + ty + r) * 1024 + by + tx] = (f16)t[tx][ty + r];
}

// ---------------- bvo = Wo @ bv + bo (batched over heads) ----------------
struct BvoArgs { const float* Wo[3]; const float* bv[3]; const float* bo[3]; float* out[3]; };
__global__ __launch_bounds__(64) void make_bvo3(BvoArgs a) {
  int h = blockIdx.y, r = blockIdx.x, l = threadIdx.x;
  const float* Wo = a.Wo[h];
  const float* bv = a.bv[h];
  float s = 0.0f;
  for (int k = l; k < 1024; k += 64) s += Wo[(long)r * 1024 + k] * bv[k];
  #pragma unroll
  for (int off = 32; off > 0; off >>= 1) s += __shfl_xor(s, off);
  if (l == 0) a.out[h][r] = s + a.bo[h][r];
}

__device__ __forceinline__ float2 block_reduce2(float a, float b) {
  #pragma unroll
  for (int off = 32; off > 0; off >>= 1) {
    a += __shfl_xor(a, off);
    b += __shfl_xor(b, off);
  }
  __shared__ float2 red[4];
  int wv = threadIdx.x >> 6;
  if ((threadIdx.x & 63) == 0) red[wv] = make_float2(a, b);
  __syncthreads();
  float2 r0 = red[0], r1 = red[1], r2 = red[2], r3 = red[3];
  return make_float2(r0.x + r1.x + r2.x + r3.x, r0.y + r1.y + r2.y + r3.y);
}

// ---------------- merged = [rmsnorm(h_prev), rmsnorm(tok)] ----------------
__global__ __launch_bounds__(256) void merge_rms(const float* __restrict__ hprev,
                                                 const float* __restrict__ embed,
                                                 const int* __restrict__ tok,
                                                 f16* __restrict__ merged, int koff,
                                                 int hsel) {
  int r = blockIdx.x;
  int b = r / NPOS, t = r - b * NPOS;
  int tid = threadIdx.x;
  const float* hrow = (hsel >= 0)
      ? embed + (long)tok[b * 512 + t + hsel] * DMODEL
      : hprev + (long)r * DMODEL;
  float4 hv = ((const float4*)hrow)[tid];
  float4 tv = ((const float4*)(embed + (long)tok[b * 512 + t + koff] * DMODEL))[tid];
  float sh = hv.x * hv.x + hv.y * hv.y + hv.z * hv.z + hv.w * hv.w;
  float st = tv.x * tv.x + tv.y * tv.y + tv.z * tv.z + tv.w * tv.w;
  float2 tot = block_reduce2(sh, st);
  float ih = 1.0f / sqrtf(tot.x * (1.0f / DMODEL) + 1e-8f);
  float it = 1.0f / sqrtf(tot.y * (1.0f / DMODEL) + 1e-8f);
  f16x4 oh = {(f16)(hv.x * ih), (f16)(hv.y * ih), (f16)(hv.z * ih), (f16)(hv.w * ih)};
  f16x4 ot = {(f16)(tv.x * it), (f16)(tv.y * it), (f16)(tv.z * it), (f16)(tv.w * it)};
  *(f16x4*)(merged + (long)r * 2048 + tid * 4) = oh;
  *(f16x4*)(merged + (long)r * 2048 + 1024 + tid * 4) = ot;
}

// ---------------- y = LN(x + res) * g + b ----------------
__global__ __launch_bounds__(256) void add_ln(const float* __restrict__ x,
                                              const float* __restrict__ res,
                                              const float* __restrict__ g,
                                              const float* __restrict__ bb,
                                              float* __restrict__ yf,
                                              f16* __restrict__ yh) {
  int r = blockIdx.x, tid = threadIdx.x;
  float4 a = ((const float4*)(x + (long)r * DMODEL))[tid];
  float4 c = ((const float4*)(res + (long)r * DMODEL))[tid];
  a.x += c.x; a.y += c.y; a.z += c.z; a.w += c.w;
  float s  = a.x + a.y + a.z + a.w;
  float ss = a.x * a.x + a.y * a.y + a.z * a.z + a.w * a.w;
  float2 tot = block_reduce2(s, ss);
  float mean = tot.x * (1.0f / DMODEL);
  float var  = tot.y * (1.0f / DMODEL) - mean * mean;
  float inv  = 1.0f / sqrtf(var + 1e-5f);
  float4 gv = ((const float4*)g)[tid];
  float4 bv = ((const float4*)bb)[tid];
  float y0 = (a.x - mean) * inv * gv.x + bv.x;
  float y1 = (a.y - mean) * inv * gv.y + bv.y;
  float y2 = (a.z - mean) * inv * gv.z + bv.z;
  float y3 = (a.w - mean) * inv * gv.w + bv.w;
  float4 o = {y0, y1, y2, y3};
  ((float4*)(yf + (long)r * DMODEL))[tid] = o;
  f16x4 oh = {(f16)y0, (f16)y1, (f16)y2, (f16)y3};
  *(f16x4*)(yh + (long)r * DMODEL + tid * 4) = oh;
}

// ---------------- small GEMM: 64x64 tile, 3-buffer depth-2 prefetch ----------------
template <int HAS_BIAS, int RELU, int WF32, int WF16, int MASK>
__global__ __launch_bounds__(256) void gemm_sm(const f16* __restrict__ A,
                                               const f16* __restrict__ B,
                                               const float* __restrict__ bias,
                                               float* __restrict__ Cf,
                                               f16* __restrict__ Ch,
                                               int K, int N, long ldc, long coff,
                                               int mval, long zsA, long zsB, long zsC) {
  __shared__ __align__(16) f16 sA[3][2048];
  __shared__ __align__(16) f16 sB[3][2048];
  const int tid  = threadIdx.x;
  const int lane = tid & 63, wv = tid >> 6;
  const int wm = wv >> 1, wn = wv & 1;
  const int bm = blockIdx.y, bn = blockIdx.x;
  const int lr = lane & 15, lk = lane >> 4;

  A += (long)blockIdx.z * zsA;
  B += (long)blockIdx.z * zsB;
  Ch += (long)blockIdx.z * zsC;

  const f16* gA = A + ((long)(bm * 64 + (tid >> 2))) * K + (tid & 3) * 8;
  const f16* gB = B + ((long)(bn * 64 + (tid >> 2))) * K + (tid & 3) * 8;

  const int aoff = (wm * 32 + lr) * 32 + lk * 8;
  const int boff = (wn * 32 + lr) * 32 + lk * 8;

  f32x4 acc[2][2] = {};

#define SSTAGE(buf, kt)                                \
  gld_lds16(gA + (long)(kt) * 32, &sA[buf][tid * 8]);  \
  gld_lds16(gB + (long)(kt) * 32, &sB[buf][tid * 8]);

  const int nk = K >> 5;
  SSTAGE(0, 0);
  SSTAGE(1, 1);

  int cur = 0, stg = 2;
  for (int kt = 0; kt < nk; ++kt) {
    if (kt + 1 < nk) { VM2; } else { VM0; }
    BAR;
    if (kt + 2 < nk) { SSTAGE(stg, kt + 2); }
    f16x8 af0 = *(const f16x8*)&sA[cur][aoff];
    f16x8 af1 = *(const f16x8*)&sA[cur][aoff + 512];
    f16x8 bf0 = *(const f16x8*)&sB[cur][boff];
    f16x8 bf1 = *(const f16x8*)&sB[cur][boff + 512];
    acc[0][0] = MFMA16(af0, bf0, acc[0][0]);
    acc[0][1] = MFMA16(af0, bf1, acc[0][1]);
    acc[1][0] = MFMA16(af1, bf0, acc[1][0]);
    acc[1][1] = MFMA16(af1, bf1, acc[1][1]);
    cur = cur == 2 ? 0 : cur + 1;
    stg = stg == 2 ? 0 : stg + 1;
  }
#undef SSTAGE

  const int row0 = bm * 64 + wm * 32 + lk * 4;
  const int col0 = bn * 64 + wn * 32 + lr;
  #pragma unroll
  for (int mi = 0; mi < 2; ++mi) {
    #pragma unroll
    for (int ni = 0; ni < 2; ++ni) {
      int col = col0 + ni * 16;
      float bs = HAS_BIAS ? bias[col] : 0.0f;
      #pragma unroll
      for (int rg = 0; rg < 4; ++rg) {
        int row = row0 + mi * 16 + rg;
        if (!MASK || row < mval) {
          float v = acc[mi][ni][rg] + bs;
          if (RELU) v = v > 0.0f ? v : 0.0f;
          if (WF32) Cf[(long)row * ldc + coff + col] = v;
          if (WF16) Ch[(long)row * N + col] = (f16)v;
        }
      }
    }
  }
}

// ---------------- PERSISTENT mega logits GEMM: M=6144, 256x256 tiles ----------------
// 120 blocks = 8 XCDs x 15 (xcd = blockIdx%8, validated by m192 swizzle wins).
// XCD x owns bm in {3x..3x+2}: its 1.5MB A slice is L2-resident for the WHOLE
// kernel (each block's bm is FIXED; A-tile re-read 25x from local L2).
// 15 blocks/XCD = 3 bm x 5 bn-offsets walk 25 rects in lockstep (bn = 5r+off):
// live B working set = 5 panels x 512KB = 2.5MB; A+B = 4.0MB = per-XCD L2.
// Fabric traffic: A 12MB + B 8x64MB = 0.52GB (was 3.14GB in the 3000-block
// dispatch). Inner K-loop: r9's 4-phase x 2-barrier BK=64 2-dbuf schedule,
// vmcnt(4)@P2/P4, chunk-XOR LDS swizzle (0 conflicts). Epilogue ni-innermost
// (4x64B consecutive -> 256B write-combining per row).
__global__ __launch_bounds__(512, 1) void gemm256x(const f16* __restrict__ A,
                                                   const f16* __restrict__ B,
                                                   float* __restrict__ C) {
  __shared__ __align__(16) f16 sA[2][2][8192];
  __shared__ __align__(16) f16 sB[2][2][8192];
  const int K = 1024;
  const int tid = threadIdx.x;
  const int lane = tid & 63;
  const int wv = tid >> 6;
  const int wm = wv >> 2, wn = wv & 3;
  const int lr = lane & 15, lk = lane >> 4;

  const int xcd = blockIdx.x & 7;
  const int idx = blockIdx.x >> 3;        // 0..14
  const int m_off = idx % 3, n_off = idx / 3;  // n_off 0..4
  const int bm = xcd * 3 + m_off;              // FIXED per block

  const int srow = tid >> 2;                         // 0..127
  const int schunk = (tid & 3) ^ ((tid >> 3) & 3);   // pre-swizzled source chunk
  const f16* gA = A + (long)(bm * 256 + srow) * K + schunk * 8;
  const long rstep = 128L * (long)K;

  const int swz = ((lr >> 1) & 3) << 3;              // elem-XOR for frag reads
  const int aoff = (((wm * 128 + lr) * 32) + lk * 8) ^ swz;  // + mi*512
  const int boff = (((wn * 64  + lr) * 32) + lk * 8) ^ swz;  // + ni*512

  const int head = bm >> 3;
  const long coff = (long)head * 32000;
  const int row0 = (bm & 7) * 256 + wm * 128 + lk * 4;

#define STG_A(s, h, ko)                                                  \
  gld_lds16(gA + (ko) + (h) * 32, &sA[s][h][tid * 8]);                   \
  gld_lds16(gA + (ko) + (h) * 32 + rstep, &sA[s][h][tid * 8 + 4096]);
#define STG_B(s, h, ko)                                                  \
  gld_lds16(gB + (ko) + (h) * 32, &sB[s][h][tid * 8]);                   \
  gld_lds16(gB + (ko) + (h) * 32 + rstep, &sB[s][h][tid * 8 + 4096]);

  for (int r = 0; r < 25; ++r) {
    const int bn = r * 5 + n_off;
    const f16* gB = B + (long)(bn * 256 + srow) * K + schunk * 8;
    f32x4 acc[8][4] = {};

    // prologue: tile 0 (stage order Ak0,Bk0,Ak1,Bk1), publish kh0
    STG_A(0, 0, 0); STG_B(0, 0, 0); STG_A(0, 1, 0); STG_B(0, 1, 0);
    VM4;
    BAR;

    const int nt = 16;  // K / 64
    for (int t = 0; t < nt; ++t) {
      const int cur = t & 1, nxt = cur ^ 1;
      const long kn = (long)((t + 1 < nt) ? (t + 1) : 0) * 64;
      f16x8 alo[4], ahi[4], bf[4];

      // ---- P1: kh0, mi 0-3 ----
      #pragma unroll
      for (int i2 = 0; i2 < 4; ++i2) alo[i2] = *(const f16x8*)&sA[cur][0][aoff + i2 * 512];
      #pragma unroll
      for (int j = 0; j < 4; ++j) bf[j] = *(const f16x8*)&sB[cur][0][boff + j * 512];
      STG_A(nxt, 0, kn);
      BAR; LGKM0; SCHED0;
      __builtin_amdgcn_s_setprio(1);
      #pragma unroll
      for (int i2 = 0; i2 < 4; ++i2)
        #pragma unroll
        for (int j = 0; j < 4; ++j)
          acc[i2][j] = MFMA16(alo[i2], bf[j], acc[i2][j]);
      __builtin_amdgcn_s_setprio(0);
      BAR;

      // ---- P2: kh0, mi 4-7 ----
      #pragma unroll
      for (int i2 = 0; i2 < 4; ++i2) ahi[i2] = *(const f16x8*)&sA[cur][0][aoff + (i2 + 4) * 512];
      STG_B(nxt, 0, kn);
      VM4;
      BAR; LGKM0; SCHED0;
      __builtin_amdgcn_s_setprio(1);
      #pragma unroll
      for (int i2 = 0; i2 < 4; ++i2)
        #pragma unroll
        for (int j = 0; j < 4; ++j)
          acc[i2 + 4][j] = MFMA16(ahi[i2], bf[j], acc[i2 + 4][j]);
      __builtin_amdgcn_s_setprio(0);
      BAR;

      // ---- P3: kh1, mi 0-3 ----
      #pragma unroll
      for (int i2 = 0; i2 < 4; ++i2) alo[i2] = *(const f16x8*)&sA[cur][1][aoff + i2 * 512];
      #pragma unroll
      for (int j = 0; j < 4; ++j) bf[j] = *(const f16x8*)&sB[cur][1][boff + j * 512];
      STG_A(nxt, 1, kn);
      BAR; LGKM0; SCHED0;
      __builtin_amdgcn_s_setprio(1);
      #pragma unroll
      for (int i2 = 0; i2 < 4; ++i2)
        #pragma unroll
        for (int j = 0; j < 4; ++j)
          acc[i2][j] = MFMA16(alo[i2], bf[j], acc[i2][j]);
      __builtin_amdgcn_s_setprio(0);
      BAR;

      // ---- P4: kh1, mi 4-7 ----
      #pragma unroll
      for (int i2 = 0; i2 < 4; ++i2) ahi[i2] = *(const f16x8*)&sA[cur][1][aoff + (i2 + 4) * 512];
      STG_B(nxt, 1, kn);
      VM4;
      BAR; LGKM0; SCHED0;
      __builtin_amdgcn_s_setprio(1);
      #pragma unroll
      for (int i2 = 0; i2 < 4; ++i2)
        #pragma unroll
        for (int j = 0; j < 4; ++j)
          acc[i2 + 4][j] = MFMA16(ahi[i2], bf[j], acc[i2 + 4][j]);
      __builtin_amdgcn_s_setprio(0);
      BAR;
    }
    VM0;  // drain wrap stages (next rect's prologue restages buf0 cleanly)

    // epilogue: ni innermost -> 4 consecutive 64B stores per row (256B runs)
    const int col0 = bn * 256 + wn * 64 + lr;
    #pragma unroll
    for (int mi = 0; mi < 8; ++mi) {
      #pragma unroll
      for (int rg = 0; rg < 4; ++rg) {
        int row = row0 + mi * 16 + rg;
        if (row < MROWS) {
          float* crow = C + (long)row * 96000 + coff;
          #pragma unroll
          for (int ni = 0; ni < 4; ++ni)
            crow[col0 + ni * 16] = acc[mi][ni][rg];
        }
      }
    }
  }
#undef STG_A
#undef STG_B
}

// ---------------- host-side orchestration ----------------
extern "C" void kernel_launch(void* const* d_in, const int* in_sizes, int n_in,
                              void* d_out, int out_size, void* d_ws, size_t ws_size,
                              hipStream_t stream) {
  const int*   tok   = (const int*)d_in[0];
  const float* embed = (const float*)d_in[1];
  auto P = [&](int k, int j) { return (const float*)d_in[2 + k * 14 + j]; };
  float* out = (float*)d_out;

  char* w = (char*)d_ws;
  auto alloc = [&](size_t bytes) { char* p = w; w += bytes; return p; };
  const size_t MM = (size_t)1024 * 1024;

  f16* embed_h = (f16*)alloc((size_t)32000 * 1024 * 2);
  f16* Wo_all  = (f16*)alloc(3 * MM * 2);
  f16* Wvo_all = (f16*)alloc(3 * MM * 2);
  f16 *Wm_h[3], *W1_h[3], *W2_h[3];
  for (int k = 0; k < 3; ++k) {
    Wm_h[k]  = (f16*)alloc((size_t)1024 * 2048 * 2);
    W1_h[k]  = (f16*)alloc((size_t)2048 * 1024 * 2);
    W2_h[k]  = (f16*)alloc((size_t)1024 * 2048 * 2);
  }
  float* hprev  = (float*)alloc((size_t)MPAD * 1024 * 4);
  f16*   h_all  = (f16*)alloc((size_t)3 * MPAD * 1024 * 2);
  f16*   merged = (f16*)alloc((size_t)MPAD * 2048 * 2);
  float* xf     = (float*)alloc((size_t)MPAD * 1024 * 4);
  f16*   xh     = (f16*)alloc((size_t)MPAD * 1024 * 2);
  f16*   ff1    = (f16*)alloc((size_t)MPAD * 2048 * 2);
  float* t1     = (float*)alloc((size_t)MPAD * 1024 * 4);
  float* bvo    = (float*)alloc(3 * 1024 * 4);
  f16* WvT_all = merged;  // scratch overlay (merged written later, stream-ordered)

  // ---- prep ----
  conv_f32_f16<<<16000, 256, 0, stream>>>(embed, embed_h, (long)32000 * 1024);

  ConvArgs ca;
  for (int k = 0; k < 3; ++k) {
    ca.s[k*4+0] = P(k, 0); ca.d[k*4+0] = Wm_h[k];        ca.n[k*4+0] = (long)1024 * 2048;
    ca.s[k*4+1] = P(k, 4); ca.d[k*4+1] = Wo_all + k*MM;  ca.n[k*4+1] = (long)1024 * 1024;
    ca.s[k*4+2] = P(k, 6); ca.d[k*4+2] = W1_h[k];        ca.n[k*4+2] = (long)2048 * 1024;
    ca.s[k*4+3] = P(k, 8); ca.d[k*4+3] = W2_h[k];        ca.n[k*4+3] = (long)1024 * 2048;
  }
  conv_many<<<dim3(1024, 12), 256, 0, stream>>>(ca);

  TpArgs ta;
  for (int k = 0; k < 3; ++k) { ta.s[k] = P(k, 2); ta.d[k] = WvT_all + k * MM; }
  transpose3<<<dim3(32, 32, 3), 256, 0, stream>>>(ta);

  gemm_sm<0, 0, 0, 1, 0><<<dim3(16, 16, 3), 256, 0, stream>>>(
      Wo_all, WvT_all, nullptr, nullptr, Wvo_all, 1024, 1024, 1024L, 0L, 1024,
      (long)MM, (long)MM, (long)MM);

  BvoArgs ba;
  for (int k = 0; k < 3; ++k) {
    ba.Wo[k] = P(k, 4); ba.bv[k] = P(k, 3); ba.bo[k] = P(k, 5); ba.out[k] = bvo + k * 1024;
  }
  make_bvo3<<<dim3(1024, 3), 64, 0, stream>>>(ba);

  // ---- 3 encoder chains (logits deferred to one mega GEMM) ----
  for (int k = 0; k < 3; ++k) {
    merge_rms<<<MROWS, 256, 0, stream>>>(hprev, embed, tok, merged, k + 1,
                                         k == 0 ? 0 : -1);
    gemm_sm<1, 0, 1, 1, 0><<<dim3(16, 32), 256, 0, stream>>>(
        merged, Wm_h[k], P(k, 1), xf, xh, 2048, 1024, 1024L, 0L, MROWS, 0L, 0L, 0L);
    gemm_sm<1, 0, 1, 0, 0><<<dim3(16, 32), 256, 0, stream>>>(
        xh, Wvo_all + k * MM, bvo + k * 1024, t1, nullptr, 1024, 1024, 1024L, 0L,
        MROWS, 0L, 0L, 0L);
    add_ln<<<MROWS, 256, 0, stream>>>(xf, t1, P(k, 10), P(k, 11), xf, xh);
    gemm_sm<1, 1, 0, 1, 0><<<dim3(32, 32), 256, 0, stream>>>(
        xh, W1_h[k], P(k, 7), nullptr, ff1, 1024, 2048, 2048L, 0L, MROWS, 0L, 0L, 0L);
    gemm_sm<1, 0, 1, 0, 0><<<dim3(16, 32), 256, 0, stream>>>(
        ff1, W2_h[k], P(k, 9), t1, nullptr, 2048, 1024, 1024L, 0L, MROWS, 0L, 0L, 0L);
    add_ln<<<MROWS, 256, 0, stream>>>(xf, t1, P(k, 12), P(k, 13), hprev,
                                      h_all + (size_t)k * MPAD * 1024);
  }

  // ---- persistent rect-resident logits GEMM ----
  gemm256x<<<dim3(120), 512, 0, stream>>>(h_all, embed_h, out);
}

// Round 14
// 1295.483 us; speedup vs baseline: 1.2345x; 1.2345x over previous
//
#include <hip/hip_runtime.h>

// SimpleMTP: 3 sequential MTP heads on MI355X.
// f16 MFMA everywhere heavy; f32 residual/norms.
// Logits: r12 kernel verbatim (best measured: 586us) - 256x256, BK=64,
//   4-phase x 2-barrier, vmcnt(4)@P2/P4, rectangle XCD swizzle, XOR-swizzled LDS.
// Small GEMMs: NEW gemm_md 128x128 (r11-verified geometry: 4 waves, wave-tile
//   64x64, BK=32 3-slot ring depth-2, vmcnt(4) ledger) -> halves operand
//   re-read traffic vs 64x64 (saves ~1.35 GB over 3 heads).
// Wv/Wo fused into Wvo = Wo@Wv (precomputed per call).

#define NPOS   509
#define MROWS  2036
#define MPAD   2048
#define DMODEL 1024

typedef _Float16 f16;
typedef _Float16 f16x8 __attribute__((ext_vector_type(8)));
typedef _Float16 f16x4 __attribute__((ext_vector_type(4)));
typedef float    f32x4 __attribute__((ext_vector_type(4)));

#define MFMA16(a, b, c) __builtin_amdgcn_mfma_f32_16x16x32_f16(a, b, c, 0, 0, 0)
#define VM0   asm volatile("s_waitcnt vmcnt(0)" ::: "memory")
#define VM4   asm volatile("s_waitcnt vmcnt(4)" ::: "memory")
#define LGKM0 asm volatile("s_waitcnt lgkmcnt(0)" ::: "memory")
#define SCHED0 __builtin_amdgcn_sched_barrier(0)
#define BAR   asm volatile("s_barrier" ::: "memory")

__device__ __forceinline__ void gld_lds16(const void* g, void* l) {
  __builtin_amdgcn_global_load_lds(
      (const __attribute__((address_space(1))) void*)g,
      (__attribute__((address_space(3))) void*)l, 16, 0, 0);
}

// ---------------- f32 -> f16 convert: embed ----------------
__global__ __launch_bounds__(256) void conv_f32_f16(const float* __restrict__ src,
                                                    f16* __restrict__ dst, long n) {
  long i = ((long)blockIdx.x * 256 + threadIdx.x) * 8;
  if (i + 8 <= n) {
    float4 a = *(const float4*)(src + i);
    float4 b = *(const float4*)(src + i + 4);
    f16x8 o = {(f16)a.x, (f16)a.y, (f16)a.z, (f16)a.w,
               (f16)b.x, (f16)b.y, (f16)b.z, (f16)b.w};
    *(f16x8*)(dst + i) = o;
  }
}

// ---------------- batched weight conversion (12 tensors) ----------------
struct ConvArgs { const float* s[12]; f16* d[12]; long n[12]; };
__global__ __launch_bounds__(256) void conv_many(ConvArgs a) {
  int t = blockIdx.y;
  long i = ((long)blockIdx.x * 256 + threadIdx.x) * 8;
  if (i + 8 <= a.n[t]) {
    const float* src = a.s[t];
    float4 x = *(const float4*)(src + i);
    float4 y = *(const float4*)(src + i + 4);
    f16x8 o = {(f16)x.x, (f16)x.y, (f16)x.z, (f16)x.w,
               (f16)y.x, (f16)y.y, (f16)y.z, (f16)y.w};
    *(f16x8*)(a.d[t] + i) = o;
  }
}

// ---------------- batched 1024x1024 transpose f32->f16 (Wv -> WvT) ----------------
struct TpArgs { const float* s[3]; f16* d[3]; };
__global__ __launch_bounds__(256) void transpose3(TpArgs a) {
  __shared__ float t[32][33];
  int h = blockIdx.z;
  int bx = blockIdx.x * 32, by = blockIdx.y * 32;
  int tx = threadIdx.x & 31, ty = threadIdx.x >> 5;
  const float* src = a.s[h];
  f16* dst = a.d[h];
  #pragma unroll
  for (int r = 0; r < 32; r += 8)
    t[ty + r][tx] = src[(long)(by + ty + r) * 1024 + bx + tx];
  __syncthreads();
  #pragma unroll
  for (int r = 0; r < 32; r += 8)
    dst[(long)(bx + ty + r) * 1024 + by + tx] = (f16)t[tx][ty + r];
}

// ---------------- bvo = Wo @ bv + bo (batched over heads) ----------------
struct BvoArgs { const float* Wo[3]; const float* bv[3]; const float* bo[3]; float* out[3]; };
__global__ __launch_bounds__(64) void make_bvo3(BvoArgs a) {
  int h = blockIdx.y, r = blockIdx.x, l = threadIdx.x;
  const float* Wo = a.Wo[h];
  const float* bv = a.bv[h];
  float s = 0.0f;
  for (int k = l; k < 1024; k += 64) s += Wo[(long)r * 1024 + k] * bv[k];
  #pragma unroll
  for (int off = 32; off > 0; off >>= 1) s += __shfl_xor(s, off);
  if (l == 0) a.out[h][r] = s + a.bo[h][r];
}

__device__ __forceinline__ float2 block_reduce2(float a, float b) {
  #pragma unroll
  for (int off = 32; off > 0; off >>= 1) {
    a += __shfl_xor(a, off);
    b += __shfl_xor(b, off);
  }
  __shared__ float2 red[4];
  int wv = threadIdx.x >> 6;
  if ((threadIdx.x & 63) == 0) red[wv] = make_float2(a, b);
  __syncthreads();
  float2 r0 = red[0], r1 = red[1], r2 = red[2], r3 = red[3];
  return make_float2(r0.x + r1.x + r2.x + r3.x, r0.y + r1.y + r2.y + r3.y);
}

// ---------------- merged = [rmsnorm(h_prev), rmsnorm(tok)] ----------------
__global__ __launch_bounds__(256) void merge_rms(const float* __restrict__ hprev,
                                                 const float* __restrict__ embed,
                                                 const int* __restrict__ tok,
                                                 f16* __restrict__ merged, int koff,
                                                 int hsel) {
  int r = blockIdx.x;
  int b = r / NPOS, t = r - b * NPOS;
  int tid = threadIdx.x;
  const float* hrow = (hsel >= 0)
      ? embed + (long)tok[b * 512 + t + hsel] * DMODEL
      : hprev + (long)r * DMODEL;
  float4 hv = ((const float4*)hrow)[tid];
  float4 tv = ((const float4*)(embed + (long)tok[b * 512 + t + koff] * DMODEL))[tid];
  float sh = hv.x * hv.x + hv.y * hv.y + hv.z * hv.z + hv.w * hv.w;
  float st = tv.x * tv.x + tv.y * tv.y + tv.z * tv.z + tv.w * tv.w;
  float2 tot = block_reduce2(sh, st);
  float ih = 1.0f / sqrtf(tot.x * (1.0f / DMODEL) + 1e-8f);
  float it = 1.0f / sqrtf(tot.y * (1.0f / DMODEL) + 1e-8f);
  f16x4 oh = {(f16)(hv.x * ih), (f16)(hv.y * ih), (f16)(hv.z * ih), (f16)(hv.w * ih)};
  f16x4 ot = {(f16)(tv.x * it), (f16)(tv.y * it), (f16)(tv.z * it), (f16)(tv.w * it)};
  *(f16x4*)(merged + (long)r * 2048 + tid * 4) = oh;
  *(f16x4*)(merged + (long)r * 2048 + 1024 + tid * 4) = ot;
}

// ---------------- y = LN(x + res) * g + b ----------------
__global__ __launch_bounds__(256) void add_ln(const float* __restrict__ x,
                                              const float* __restrict__ res,
                                              const float* __restrict__ g,
                                              const float* __restrict__ bb,
                                              float* __restrict__ yf,
                                              f16* __restrict__ yh) {
  int r = blockIdx.x, tid = threadIdx.x;
  float4 a = ((const float4*)(x + (long)r * DMODEL))[tid];
  float4 c = ((const float4*)(res + (long)r * DMODEL))[tid];
  a.x += c.x; a.y += c.y; a.z += c.z; a.w += c.w;
  float s  = a.x + a.y + a.z + a.w;
  float ss = a.x * a.x + a.y * a.y + a.z * a.z + a.w * a.w;
  float2 tot = block_reduce2(s, ss);
  float mean = tot.x * (1.0f / DMODEL);
  float var  = tot.y * (1.0f / DMODEL) - mean * mean;
  float inv  = 1.0f / sqrtf(var + 1e-5f);
  float4 gv = ((const float4*)g)[tid];
  float4 bv = ((const float4*)bb)[tid];
  float y0 = (a.x - mean) * inv * gv.x + bv.x;
  float y1 = (a.y - mean) * inv * gv.y + bv.y;
  float y2 = (a.z - mean) * inv * gv.z + bv.z;
  float y3 = (a.w - mean) * inv * gv.w + bv.w;
  float4 o = {y0, y1, y2, y3};
  ((float4*)(yf + (long)r * DMODEL))[tid] = o;
  f16x4 oh = {(f16)y0, (f16)y1, (f16)y2, (f16)y3};
  *(f16x4*)(yh + (long)r * DMODEL + tid * 4) = oh;
}

// ---------------- small/medium GEMM: 128x128 tile, 3-slot ring depth-2 ----------------
// Port of the r11-verified 128x128 geometry: 4 waves (2M x 2N), wave tile
// 64x64 (acc 64 VGPR), BK=32, 3-slot ring, prefetch distance 2, vmcnt(4)
// ledger (4 loads/thread/tile: at P2-end outstanding = t+1's 4 + t+2's 4 = 8;
// vmcnt(4) retires exactly t+1's; end-BAR publishes). Chunk-XOR LDS swizzle.
// LDS 48 KB -> 3 blocks/CU. Halves operand re-read traffic vs 64x64 tiles.
template <int HAS_BIAS, int RELU, int WF32, int WF16>
__global__ __launch_bounds__(256, 3) void gemm_md(const f16* __restrict__ A,
                                                  const f16* __restrict__ B,
                                                  const float* __restrict__ bias,
                                                  float* __restrict__ Cf,
                                                  f16* __restrict__ Ch,
                                                  int K, int N, long ldc,
                                                  int mval, long zsA, long zsB, long zsC) {
  __shared__ __align__(16) f16 sA[3][4096];  // 128 x 32
  __shared__ __align__(16) f16 sB[3][4096];  // 128 x 32
  const int tid = threadIdx.x;
  const int lane = tid & 63;
  const int wv = tid >> 6;
  const int wm = wv >> 1, wn = wv & 1;
  const int lr = lane & 15, lk = lane >> 4;
  const int bm = blockIdx.y, bn = blockIdx.x;

  A += (long)blockIdx.z * zsA;
  B += (long)blockIdx.z * zsB;
  Ch += (long)blockIdx.z * zsC;

  const int srow = tid >> 2;                        // 0..63
  const int schunk = (tid & 3) ^ ((tid >> 3) & 3);  // pre-swizzled source chunk
  const f16* gA = A + (long)(bm * 128 + srow) * K + schunk * 8;
  const f16* gB = B + (long)(bn * 128 + srow) * K + schunk * 8;

  const int swz = ((lr >> 1) & 3) << 3;             // lane-constant read XOR
  const int aoff = (((wm * 64 + lr) * 32) + lk * 8) ^ swz;  // + mi*512
  const int boff = (((wn * 64 + lr) * 32) + lk * 8) ^ swz;  // + ni*512

  f32x4 acc[4][4] = {};

#define STG_A(s, kt, i) gld_lds16(gA + (long)(kt) * 32 + (long)(i) * 64 * K, \
                                  &sA[s][(i) * 2048 + tid * 8]);
#define STG_B(s, kt, j) gld_lds16(gB + (long)(kt) * 32 + (long)(j) * 64 * K, \
                                  &sB[s][(j) * 2048 + tid * 8]);
#define STAGE_H1(s, kt) STG_A(s, kt, 0) STG_B(s, kt, 0)
#define STAGE_H2(s, kt) STG_A(s, kt, 1) STG_B(s, kt, 1)

  // prologue: tiles 0,1 (8 loads); vmcnt(4) retires tile 0; BAR publishes.
  STAGE_H1(0, 0) STAGE_H2(0, 0)
  STAGE_H1(1, 1) STAGE_H2(1, 1)
  VM4; BAR;

  const int nt = K >> 5;
  int slot = 0;
  for (int t = 0; t < nt; ++t) {
    const int s2 = (slot >= 1) ? slot - 1 : slot + 2;       // (t+2) % 3
    const int kt2 = (t + 2 < nt) ? (t + 2) : (t + 2 - nt);  // wrap keeps ledger uniform
    f16x8 af[4], bf[4];

    // ---- P1: ni 0-1 ----
    STAGE_H1(s2, kt2)
    #pragma unroll
    for (int i = 0; i < 4; ++i) af[i] = *(const f16x8*)&sA[slot][aoff + i * 512];
    bf[0] = *(const f16x8*)&sB[slot][boff];
    bf[1] = *(const f16x8*)&sB[slot][boff + 512];
    LGKM0; SCHED0;
    __builtin_amdgcn_s_setprio(1);
    #pragma unroll
    for (int i = 0; i < 4; ++i) {
      acc[i][0] = MFMA16(af[i], bf[0], acc[i][0]);
      acc[i][1] = MFMA16(af[i], bf[1], acc[i][1]);
    }
    __builtin_amdgcn_s_setprio(0);
    BAR;

    // ---- P2: ni 2-3 ----
    STAGE_H2(s2, kt2)
    bf[2] = *(const f16x8*)&sB[slot][boff + 1024];
    bf[3] = *(const f16x8*)&sB[slot][boff + 1536];
    LGKM0; SCHED0;
    __builtin_amdgcn_s_setprio(1);
    #pragma unroll
    for (int i = 0; i < 4; ++i) {
      acc[i][2] = MFMA16(af[i], bf[2], acc[i][2]);
      acc[i][3] = MFMA16(af[i], bf[3], acc[i][3]);
    }
    __builtin_amdgcn_s_setprio(0);
    VM4;   // retires tile t+1's 4 loads; next BAR publishes them
    BAR;

    slot = (slot == 2) ? 0 : slot + 1;
  }
  VM0;  // drain wrap stages

  const int row0 = bm * 128 + wm * 64 + lk * 4;
  const int col0 = bn * 128 + wn * 64 + lr;
  #pragma unroll
  for (int mi = 0; mi < 4; ++mi) {
    #pragma unroll
    for (int ni = 0; ni < 4; ++ni) {
      int col = col0 + ni * 16;
      float bs = HAS_BIAS ? bias[col] : 0.0f;
      #pragma unroll
      for (int rg = 0; rg < 4; ++rg) {
        int row = row0 + mi * 16 + rg;
        if (row < mval) {
          float v = acc[mi][ni][rg] + bs;
          if (RELU) v = v > 0.0f ? v : 0.0f;
          if (WF32) Cf[(long)row * ldc + col] = v;
          if (WF16) Ch[(long)row * N + col] = (f16)v;
        }
      }
    }
  }
#undef STG_A
#undef STG_B
#undef STAGE_H1
#undef STAGE_H2
}

// ---------------- mega logits GEMM: M=6144 (3 heads), 256x256 tile ----------------
// r12 kernel verbatim (best measured 586us). BK=64, 2 dbuf, 4 phases/K-tile,
// vmcnt(4)@P2/P4, rectangle XCD swizzle, chunk-XOR LDS swizzle.
__global__ __launch_bounds__(512, 2) void gemm256x(const f16* __restrict__ A,
                                                   const f16* __restrict__ B,
                                                   float* __restrict__ C) {
  __shared__ __align__(16) f16 sA[2][2][8192];
  __shared__ __align__(16) f16 sB[2][2][8192];
  const int K = 1024;
  const int tid = threadIdx.x;
  const int lane = tid & 63;
  const int wv = tid >> 6;
  const int wm = wv >> 2, wn = wv & 3;
  const int lr = lane & 15, lk = lane >> 4;

  const int flat = blockIdx.y * 125 + blockIdx.x;
  const int xcd = flat & 7, i = flat >> 3;
  const int grp = i / 15, w = i % 15;
  const int bm = xcd * 3 + (w % 3);
  const int bn = grp * 5 + (w / 3);

  const int srow = tid >> 2;
  const int schunk = (tid & 3) ^ ((tid >> 3) & 3);
  const f16* gA = A + (long)(bm * 256 + srow) * K + schunk * 8;
  const f16* gB = B + (long)(bn * 256 + srow) * K + schunk * 8;
  const long rstep = 128L * (long)K;

  const int swz = ((lr >> 1) & 3) << 3;
  const int aoff = (((wm * 128 + lr) * 32) + lk * 8) ^ swz;
  const int boff = (((wn * 64  + lr) * 32) + lk * 8) ^ swz;

  f32x4 acc[8][4] = {};

#define STG_A(s, h, ko)                                                  \
  gld_lds16(gA + (ko) + (h) * 32, &sA[s][h][tid * 8]);                   \
  gld_lds16(gA + (ko) + (h) * 32 + rstep, &sA[s][h][tid * 8 + 4096]);
#define STG_B(s, h, ko)                                                  \
  gld_lds16(gB + (ko) + (h) * 32, &sB[s][h][tid * 8]);                   \
  gld_lds16(gB + (ko) + (h) * 32 + rstep, &sB[s][h][tid * 8 + 4096]);

  STG_A(0, 0, 0); STG_B(0, 0, 0); STG_A(0, 1, 0); STG_B(0, 1, 0);
  VM4;
  BAR;

  const int nt = 16;
  for (int t = 0; t < nt; ++t) {
    const int cur = t & 1, nxt = cur ^ 1;
    const long kn = (long)((t + 1 < nt) ? (t + 1) : 0) * 64;
    f16x8 alo[4], ahi[4], bf[4];

    // ---- P1: kh0, mi 0-3 ----
    #pragma unroll
    for (int i2 = 0; i2 < 4; ++i2) alo[i2] = *(const f16x8*)&sA[cur][0][aoff + i2 * 512];
    #pragma unroll
    for (int j = 0; j < 4; ++j) bf[j] = *(const f16x8*)&sB[cur][0][boff + j * 512];
    STG_A(nxt, 0, kn);
    BAR; LGKM0; SCHED0;
    __builtin_amdgcn_s_setprio(1);
    #pragma unroll
    for (int i2 = 0; i2 < 4; ++i2)
      #pragma unroll
      for (int j = 0; j < 4; ++j)
        acc[i2][j] = MFMA16(alo[i2], bf[j], acc[i2][j]);
    __builtin_amdgcn_s_setprio(0);
    BAR;

    // ---- P2: kh0, mi 4-7 ----
    #pragma unroll
    for (int i2 = 0; i2 < 4; ++i2) ahi[i2] = *(const f16x8*)&sA[cur][0][aoff + (i2 + 4) * 512];
    STG_B(nxt, 0, kn);
    VM4;
    BAR; LGKM0; SCHED0;
    __builtin_amdgcn_s_setprio(1);
    #pragma unroll
    for (int i2 = 0; i2 < 4; ++i2)
      #pragma unroll
      for (int j = 0; j < 4; ++j)
        acc[i2 + 4][j] = MFMA16(ahi[i2], bf[j], acc[i2 + 4][j]);
    __builtin_amdgcn_s_setprio(0);
    BAR;

    // ---- P3: kh1, mi 0-3 ----
    #pragma unroll
    for (int i2 = 0; i2 < 4; ++i2) alo[i2] = *(const f16x8*)&sA[cur][1][aoff + i2 * 512];
    #pragma unroll
    for (int j = 0; j < 4; ++j) bf[j] = *(const f16x8*)&sB[cur][1][boff + j * 512];
    STG_A(nxt, 1, kn);
    BAR; LGKM0; SCHED0;
    __builtin_amdgcn_s_setprio(1);
    #pragma unroll
    for (int i2 = 0; i2 < 4; ++i2)
      #pragma unroll
      for (int j = 0; j < 4; ++j)
        acc[i2][j] = MFMA16(alo[i2], bf[j], acc[i2][j]);
    __builtin_amdgcn_s_setprio(0);
    BAR;

    // ---- P4: kh1, mi 4-7 ----
    #pragma unroll
    for (int i2 = 0; i2 < 4; ++i2) ahi[i2] = *(const f16x8*)&sA[cur][1][aoff + (i2 + 4) * 512];
    STG_B(nxt, 1, kn);
    VM4;
    BAR; LGKM0; SCHED0;
    __builtin_amdgcn_s_setprio(1);
    #pragma unroll
    for (int i2 = 0; i2 < 4; ++i2)
      #pragma unroll
      for (int j = 0; j < 4; ++j)
        acc[i2 + 4][j] = MFMA16(ahi[i2], bf[j], acc[i2 + 4][j]);
    __builtin_amdgcn_s_setprio(0);
    BAR;
  }
  VM0;

  const int head = bm >> 3;
  const long coff = (long)head * 32000;
  const int row0 = (bm & 7) * 256 + wm * 128 + lk * 4;
  const int col0 = bn * 256 + wn * 64 + lr;
  #pragma unroll
  for (int mi = 0; mi < 8; ++mi) {
    #pragma unroll
    for (int ni = 0; ni < 4; ++ni) {
      int col = col0 + ni * 16;
      #pragma unroll
      for (int rg = 0; rg < 4; ++rg) {
        int row = row0 + mi * 16 + rg;
        if (row < MROWS) C[(long)row * 96000 + coff + col] = acc[mi][ni][rg];
      }
    }
  }
#undef STG_A
#undef STG_B
}

// ---------------- host-side orchestration ----------------
extern "C" void kernel_launch(void* const* d_in, const int* in_sizes, int n_in,
                              void* d_out, int out_size, void* d_ws, size_t ws_size,
                              hipStream_t stream) {
  const int*   tok   = (const int*)d_in[0];
  const float* embed = (const float*)d_in[1];
  auto P = [&](int k, int j) { return (const float*)d_in[2 + k * 14 + j]; };
  float* out = (float*)d_out;

  char* w = (char*)d_ws;
  auto alloc = [&](size_t bytes) { char* p = w; w += bytes; return p; };
  const size_t MM = (size_t)1024 * 1024;

  f16* embed_h = (f16*)alloc((size_t)32000 * 1024 * 2);
  f16* Wo_all  = (f16*)alloc(3 * MM * 2);
  f16* Wvo_all = (f16*)alloc(3 * MM * 2);
  f16 *Wm_h[3], *W1_h[3], *W2_h[3];
  for (int k = 0; k < 3; ++k) {
    Wm_h[k]  = (f16*)alloc((size_t)1024 * 2048 * 2);
    W1_h[k]  = (f16*)alloc((size_t)2048 * 1024 * 2);
    W2_h[k]  = (f16*)alloc((size_t)1024 * 2048 * 2);
  }
  float* hprev  = (float*)alloc((size_t)MPAD * 1024 * 4);
  f16*   h_all  = (f16*)alloc((size_t)3 * MPAD * 1024 * 2);
  f16*   merged = (f16*)alloc((size_t)MPAD * 2048 * 2);
  float* xf     = (float*)alloc((size_t)MPAD * 1024 * 4);
  f16*   xh     = (f16*)alloc((size_t)MPAD * 1024 * 2);
  f16*   ff1    = (f16*)alloc((size_t)MPAD * 2048 * 2);
  float* t1     = (float*)alloc((size_t)MPAD * 1024 * 4);
  float* bvo    = (float*)alloc(3 * 1024 * 4);
  f16* WvT_all = merged;  // scratch overlay (merged written later, stream-ordered)

  // ---- prep ----
  conv_f32_f16<<<16000, 256, 0, stream>>>(embed, embed_h, (long)32000 * 1024);

  ConvArgs ca;
  for (int k = 0; k < 3; ++k) {
    ca.s[k*4+0] = P(k, 0); ca.d[k*4+0] = Wm_h[k];        ca.n[k*4+0] = (long)1024 * 2048;
    ca.s[k*4+1] = P(k, 4); ca.d[k*4+1] = Wo_all + k*MM;  ca.n[k*4+1] = (long)1024 * 1024;
    ca.s[k*4+2] = P(k, 6); ca.d[k*4+2] = W1_h[k];        ca.n[k*4+2] = (long)2048 * 1024;
    ca.s[k*4+3] = P(k, 8); ca.d[k*4+3] = W2_h[k];        ca.n[k*4+3] = (long)1024 * 2048;
  }
  conv_many<<<dim3(1024, 12), 256, 0, stream>>>(ca);

  TpArgs ta;
  for (int k = 0; k < 3; ++k) { ta.s[k] = P(k, 2); ta.d[k] = WvT_all + k * MM; }
  transpose3<<<dim3(32, 32, 3), 256, 0, stream>>>(ta);

  // Wvo[k] = Wo[k] @ WvT[k]  (batched over z, 128x128 tiles)
  gemm_md<0, 0, 0, 1><<<dim3(8, 8, 3), 256, 0, stream>>>(
      Wo_all, WvT_all, nullptr, nullptr, Wvo_all, 1024, 1024, 1024L, 1024,
      (long)MM, (long)MM, (long)MM);

  BvoArgs ba;
  for (int k = 0; k < 3; ++k) {
    ba.Wo[k] = P(k, 4); ba.bv[k] = P(k, 3); ba.bo[k] = P(k, 5); ba.out[k] = bvo + k * 1024;
  }
  make_bvo3<<<dim3(1024, 3), 64, 0, stream>>>(ba);

  // ---- 3 encoder chains (logits deferred to one mega GEMM) ----
  for (int k = 0; k < 3; ++k) {
    merge_rms<<<MROWS, 256, 0, stream>>>(hprev, embed, tok, merged, k + 1,
                                         k == 0 ? 0 : -1);
    // x = merged @ Wmerge^T + bmerge
    gemm_md<1, 0, 1, 1><<<dim3(8, 16), 256, 0, stream>>>(
        merged, Wm_h[k], P(k, 1), xf, xh, 2048, 1024, 1024L, MPAD, 0L, 0L, 0L);
    // attn = x @ Wvo^T + bvo
    gemm_md<1, 0, 1, 0><<<dim3(8, 16), 256, 0, stream>>>(
        xh, Wvo_all + k * MM, bvo + k * 1024, t1, nullptr, 1024, 1024, 1024L,
        MPAD, 0L, 0L, 0L);
    add_ln<<<MROWS, 256, 0, stream>>>(xf, t1, P(k, 10), P(k, 11), xf, xh);
    // ff1 = relu(x @ W1^T + b1)
    gemm_md<1, 1, 0, 1><<<dim3(16, 16), 256, 0, stream>>>(
        xh, W1_h[k], P(k, 7), nullptr, ff1, 1024, 2048, 2048L, MPAD, 0L, 0L, 0L);
    // ff = ff1 @ W2^T + b2
    gemm_md<1, 0, 1, 0><<<dim3(8, 16), 256, 0, stream>>>(
        ff1, W2_h[k], P(k, 9), t1, nullptr, 2048, 1024, 1024L, MPAD, 0L, 0L, 0L);
    add_ln<<<MROWS, 256, 0, stream>>>(xf, t1, P(k, 12), P(k, 13), hprev,
                                      h_all + (size_t)k * MPAD * 1024);
  }

  // ---- one mega logits GEMM (r12 kernel) ----
  gemm256x<<<dim3(125, 24), 512, 0, stream>>>(h_all, embed_h, out);
}

// Round 15
// 967.960 us; speedup vs baseline: 1.6522x; 1.3384x over previous
//
#include <hip/hip_runtime.h>

// SimpleMTP: 3 sequential MTP heads on MI355X.
// f16 MFMA everywhere heavy; f32 residual/norms.
// Logits: 256x256 tile, BK=32, 4-slot ring, prefetch distance 3 (~1400cyc,
//   covers L3-miss stragglers), 2 fine phases/tile, ONE barrier + vmcnt(8)
//   per tile, rectangle XCD swizzle, chunk-XOR LDS swizzle.
// Small GEMMs: r12 gemm_sm verbatim (64x64, 3-buffer depth-2, 512 blocks).
// Wv/Wo fused into Wvo = Wo@Wv (precomputed per call).

#define NPOS   509
#define MROWS  2036
#define MPAD   2048
#define DMODEL 1024

typedef _Float16 f16;
typedef _Float16 f16x8 __attribute__((ext_vector_type(8)));
typedef _Float16 f16x4 __attribute__((ext_vector_type(4)));
typedef float    f32x4 __attribute__((ext_vector_type(4)));

#define MFMA16(a, b, c) __builtin_amdgcn_mfma_f32_16x16x32_f16(a, b, c, 0, 0, 0)
#define VM0   asm volatile("s_waitcnt vmcnt(0)" ::: "memory")
#define VM2   asm volatile("s_waitcnt vmcnt(2)" ::: "memory")
#define VM8   asm volatile("s_waitcnt vmcnt(8)" ::: "memory")
#define LGKM0 asm volatile("s_waitcnt lgkmcnt(0)" ::: "memory")
#define SCHED0 __builtin_amdgcn_sched_barrier(0)
#define BAR   asm volatile("s_barrier" ::: "memory")

__device__ __forceinline__ void gld_lds16(const void* g, void* l) {
  __builtin_amdgcn_global_load_lds(
      (const __attribute__((address_space(1))) void*)g,
      (__attribute__((address_space(3))) void*)l, 16, 0, 0);
}

// ---------------- f32 -> f16 convert: embed ----------------
__global__ __launch_bounds__(256) void conv_f32_f16(const float* __restrict__ src,
                                                    f16* __restrict__ dst, long n) {
  long i = ((long)blockIdx.x * 256 + threadIdx.x) * 8;
  if (i + 8 <= n) {
    float4 a = *(const float4*)(src + i);
    float4 b = *(const float4*)(src + i + 4);
    f16x8 o = {(f16)a.x, (f16)a.y, (f16)a.z, (f16)a.w,
               (f16)b.x, (f16)b.y, (f16)b.z, (f16)b.w};
    *(f16x8*)(dst + i) = o;
  }
}

// ---------------- batched weight conversion (12 tensors) ----------------
struct ConvArgs { const float* s[12]; f16* d[12]; long n[12]; };
__global__ __launch_bounds__(256) void conv_many(ConvArgs a) {
  int t = blockIdx.y;
  long i = ((long)blockIdx.x * 256 + threadIdx.x) * 8;
  if (i + 8 <= a.n[t]) {
    const float* src = a.s[t];
    float4 x = *(const float4*)(src + i);
    float4 y = *(const float4*)(src + i + 4);
    f16x8 o = {(f16)x.x, (f16)x.y, (f16)x.z, (f16)x.w,
               (f16)y.x, (f16)y.y, (f16)y.z, (f16)y.w};
    *(f16x8*)(a.d[t] + i) = o;
  }
}

// ---------------- batched 1024x1024 transpose f32->f16 (Wv -> WvT) ----------------
struct TpArgs { const float* s[3]; f16* d[3]; };
__global__ __launch_bounds__(256) void transpose3(TpArgs a) {
  __shared__ float t[32][33];
  int h = blockIdx.z;
  int bx = blockIdx.x * 32, by = blockIdx.y * 32;
  int tx = threadIdx.x & 31, ty = threadIdx.x >> 5;
  const float* src = a.s[h];
  f16* dst = a.d[h];
  #pragma unroll
  for (int r = 0; r < 32; r += 8)
    t[ty + r][tx] = src[(long)(by + ty + r) * 1024 + bx + tx];
  __syncthreads();
  #pragma unroll
  for (int r = 0; r < 32; r += 8)
    dst[(long)(bx + ty + r) * 1024 + by + tx] = (f16)t[tx][ty + r];
}

// ---------------- bvo = Wo @ bv + bo (batched over heads) ----------------
struct BvoArgs { const float* Wo[3]; const float* bv[3]; const float* bo[3]; float* out[3]; };
__global__ __launch_bounds__(64) void make_bvo3(BvoArgs a) {
  int h = blockIdx.y, r = blockIdx.x, l = threadIdx.x;
  const float* Wo = a.Wo[h];
  const float* bv = a.bv[h];
  float s = 0.0f;
  for (int k = l; k < 1024; k += 64) s += Wo[(long)r * 1024 + k] * bv[k];
  #pragma unroll
  for (int off = 32; off > 0; off >>= 1) s += __shfl_xor(s, off);
  if (l == 0) a.out[h][r] = s + a.bo[h][r];
}

__device__ __forceinline__ float2 block_reduce2(float a, float b) {
  #pragma unroll
  for (int off = 32; off > 0; off >>= 1) {
    a += __shfl_xor(a, off);
    b += __shfl_xor(b, off);
  }
  __shared__ float2 red[4];
  int wv = threadIdx.x >> 6;
  if ((threadIdx.x & 63) == 0) red[wv] = make_float2(a, b);
  __syncthreads();
  float2 r0 = red[0], r1 = red[1], r2 = red[2], r3 = red[3];
  return make_float2(r0.x + r1.x + r2.x + r3.x, r0.y + r1.y + r2.y + r3.y);
}

// ---------------- merged = [rmsnorm(h_prev), rmsnorm(tok)] ----------------
__global__ __launch_bounds__(256) void merge_rms(const float* __restrict__ hprev,
                                                 const float* __restrict__ embed,
                                                 const int* __restrict__ tok,
                                                 f16* __restrict__ merged, int koff,
                                                 int hsel) {
  int r = blockIdx.x;
  int b = r / NPOS, t = r - b * NPOS;
  int tid = threadIdx.x;
  const float* hrow = (hsel >= 0)
      ? embed + (long)tok[b * 512 + t + hsel] * DMODEL
      : hprev + (long)r * DMODEL;
  float4 hv = ((const float4*)hrow)[tid];
  float4 tv = ((const float4*)(embed + (long)tok[b * 512 + t + koff] * DMODEL))[tid];
  float sh = hv.x * hv.x + hv.y * hv.y + hv.z * hv.z + hv.w * hv.w;
  float st = tv.x * tv.x + tv.y * tv.y + tv.z * tv.z + tv.w * tv.w;
  float2 tot = block_reduce2(sh, st);
  float ih = 1.0f / sqrtf(tot.x * (1.0f / DMODEL) + 1e-8f);
  float it = 1.0f / sqrtf(tot.y * (1.0f / DMODEL) + 1e-8f);
  f16x4 oh = {(f16)(hv.x * ih), (f16)(hv.y * ih), (f16)(hv.z * ih), (f16)(hv.w * ih)};
  f16x4 ot = {(f16)(tv.x * it), (f16)(tv.y * it), (f16)(tv.z * it), (f16)(tv.w * it)};
  *(f16x4*)(merged + (long)r * 2048 + tid * 4) = oh;
  *(f16x4*)(merged + (long)r * 2048 + 1024 + tid * 4) = ot;
}

// ---------------- y = LN(x + res) * g + b ----------------
__global__ __launch_bounds__(256) void add_ln(const float* __restrict__ x,
                                              const float* __restrict__ res,
                                              const float* __restrict__ g,
                                              const float* __restrict__ bb,
                                              float* __restrict__ yf,
                                              f16* __restrict__ yh) {
  int r = blockIdx.x, tid = threadIdx.x;
  float4 a = ((const float4*)(x + (long)r * DMODEL))[tid];
  float4 c = ((const float4*)(res + (long)r * DMODEL))[tid];
  a.x += c.x; a.y += c.y; a.z += c.z; a.w += c.w;
  float s  = a.x + a.y + a.z + a.w;
  float ss = a.x * a.x + a.y * a.y + a.z * a.z + a.w * a.w;
  float2 tot = block_reduce2(s, ss);
  float mean = tot.x * (1.0f / DMODEL);
  float var  = tot.y * (1.0f / DMODEL) - mean * mean;
  float inv  = 1.0f / sqrtf(var + 1e-5f);
  float4 gv = ((const float4*)g)[tid];
  float4 bv = ((const float4*)bb)[tid];
  float y0 = (a.x - mean) * inv * gv.x + bv.x;
  float y1 = (a.y - mean) * inv * gv.y + bv.y;
  float y2 = (a.z - mean) * inv * gv.z + bv.z;
  float y3 = (a.w - mean) * inv * gv.w + bv.w;
  float4 o = {y0, y1, y2, y3};
  ((float4*)(yf + (long)r * DMODEL))[tid] = o;
  f16x4 oh = {(f16)y0, (f16)y1, (f16)y2, (f16)y3};
  *(f16x4*)(yh + (long)r * DMODEL + tid * 4) = oh;
}

// ---------------- small GEMM: 64x64 tile, 3-buffer depth-2 prefetch (r12) ----------------
template <int HAS_BIAS, int RELU, int WF32, int WF16, int MASK>
__global__ __launch_bounds__(256) void gemm_sm(const f16* __restrict__ A,
                                               const f16* __restrict__ B,
                                               const float* __restrict__ bias,
                                               float* __restrict__ Cf,
                                               f16* __restrict__ Ch,
                                               int K, int N, long ldc, long coff,
                                               int mval, long zsA, long zsB, long zsC) {
  __shared__ __align__(16) f16 sA[3][2048];
  __shared__ __align__(16) f16 sB[3][2048];
  const int tid  = threadIdx.x;
  const int lane = tid & 63, wv = tid >> 6;
  const int wm = wv >> 1, wn = wv & 1;
  const int bm = blockIdx.y, bn = blockIdx.x;
  const int lr = lane & 15, lk = lane >> 4;

  A += (long)blockIdx.z * zsA;
  B += (long)blockIdx.z * zsB;
  Ch += (long)blockIdx.z * zsC;

  const f16* gA = A + ((long)(bm * 64 + (tid >> 2))) * K + (tid & 3) * 8;
  const f16* gB = B + ((long)(bn * 64 + (tid >> 2))) * K + (tid & 3) * 8;

  const int aoff = (wm * 32 + lr) * 32 + lk * 8;
  const int boff = (wn * 32 + lr) * 32 + lk * 8;

  f32x4 acc[2][2] = {};

#define SSTAGE(buf, kt)                                \
  gld_lds16(gA + (long)(kt) * 32, &sA[buf][tid * 8]);  \
  gld_lds16(gB + (long)(kt) * 32, &sB[buf][tid * 8]);

  const int nk = K >> 5;
  SSTAGE(0, 0);
  SSTAGE(1, 1);

  int cur = 0, stg = 2;
  for (int kt = 0; kt < nk; ++kt) {
    if (kt + 1 < nk) { VM2; } else { VM0; }
    BAR;
    if (kt + 2 < nk) { SSTAGE(stg, kt + 2); }
    f16x8 af0 = *(const f16x8*)&sA[cur][aoff];
    f16x8 af1 = *(const f16x8*)&sA[cur][aoff + 512];
    f16x8 bf0 = *(const f16x8*)&sB[cur][boff];
    f16x8 bf1 = *(const f16x8*)&sB[cur][boff + 512];
    acc[0][0] = MFMA16(af0, bf0, acc[0][0]);
    acc[0][1] = MFMA16(af0, bf1, acc[0][1]);
    acc[1][0] = MFMA16(af1, bf0, acc[1][0]);
    acc[1][1] = MFMA16(af1, bf1, acc[1][1]);
    cur = cur == 2 ? 0 : cur + 1;
    stg = stg == 2 ? 0 : stg + 1;
  }
#undef SSTAGE

  const int row0 = bm * 64 + wm * 32 + lk * 4;
  const int col0 = bn * 64 + wn * 32 + lr;
  #pragma unroll
  for (int mi = 0; mi < 2; ++mi) {
    #pragma unroll
    for (int ni = 0; ni < 2; ++ni) {
      int col = col0 + ni * 16;
      float bs = HAS_BIAS ? bias[col] : 0.0f;
      #pragma unroll
      for (int rg = 0; rg < 4; ++rg) {
        int row = row0 + mi * 16 + rg;
        if (!MASK || row < mval) {
          float v = acc[mi][ni][rg] + bs;
          if (RELU) v = v > 0.0f ? v : 0.0f;
          if (WF32) Cf[(long)row * ldc + coff + col] = v;
          if (WF16) Ch[(long)row * N + col] = (f16)v;
        }
      }
    }
  }
}

// ---------------- mega logits GEMM: M=6144, 256x256 tile, deep ring ----------------
// BK=32, 4-slot ring (sA/sB 4 x 16 KB each = 128 KB), prefetch distance 3
// tiles (~1400 cyc - covers the ~13% B loads that miss L3 under the write
// stream). 2 fine phases/tile: {stage 2 -> ds_read frags -> lgkmcnt(0)+
// sched_barrier(0) -> setprio 16xMFMA}; ONE vmcnt(8)+BAR per tile.
// Ledger (4 loads/thread/tile; A 2 at P1, B 2 at P2): end-of-tile in-flight
// = t+1(4)+t+2(4)+t+3(4) = 12; vmcnt(8) retires exactly tile t+1; the BAR
// publishes it for next tile's reads. Anti-overwrite: slot (t+3)%4=(t-1)%4,
// whose readers finished before tile (t-1)'s end-BAR. Prologue stages tiles
// 0-2 (12 loads), vmcnt(8) retires tile 0. Wrap-stage keeps ledger uniform.
// Rectangle XCD swizzle + chunk-XOR LDS swizzle (verified 0 conflicts).
__global__ __launch_bounds__(512, 2) void gemm256x(const f16* __restrict__ A,
                                                   const f16* __restrict__ B,
                                                   float* __restrict__ C) {
  __shared__ __align__(16) f16 sA[4][8192];  // 256 rows x 32 f16 per slot
  __shared__ __align__(16) f16 sB[4][8192];
  const int K = 1024;
  const int tid = threadIdx.x;
  const int lane = tid & 63;
  const int wv = tid >> 6;
  const int wm = wv >> 2, wn = wv & 3;
  const int lr = lane & 15, lk = lane >> 4;

  // 2D rectangle XCD swizzle (r12): 3000 blocks = 8 XCDs x 375.
  const int flat = blockIdx.y * 125 + blockIdx.x;
  const int xcd = flat & 7, i = flat >> 3;
  const int grp = i / 15, w = i % 15;
  const int bm = xcd * 3 + (w % 3);
  const int bn = grp * 5 + (w / 3);

  const int srow = tid >> 2;                         // 0..127
  const int schunk = (tid & 3) ^ ((tid >> 3) & 3);   // pre-swizzled source chunk
  const f16* gA = A + (long)(bm * 256 + srow) * K + schunk * 8;
  const f16* gB = B + (long)(bn * 256 + srow) * K + schunk * 8;
  const long rstep = 128L * (long)K;

  const int swz = ((lr >> 1) & 3) << 3;              // lane-constant read XOR
  const int aoff = (((wm * 128 + lr) * 32) + lk * 8) ^ swz;  // + mi*512
  const int boff = (((wn * 64  + lr) * 32) + lk * 8) ^ swz;  // + ni*512

  f32x4 acc[8][4] = {};

#define STG_A(s, kt)                                                     \
  gld_lds16(gA + (long)(kt) * 32, &sA[s][tid * 8]);                      \
  gld_lds16(gA + (long)(kt) * 32 + rstep, &sA[s][tid * 8 + 4096]);
#define STG_B(s, kt)                                                     \
  gld_lds16(gB + (long)(kt) * 32, &sB[s][tid * 8]);                      \
  gld_lds16(gB + (long)(kt) * 32 + rstep, &sB[s][tid * 8 + 4096]);

  // prologue: tiles 0,1,2 (12 loads); vmcnt(8) retires tile 0; BAR publishes.
  STG_A(0, 0) STG_B(0, 0)
  STG_A(1, 1) STG_B(1, 1)
  STG_A(2, 2) STG_B(2, 2)
  VM8; BAR;

  const int nt = 32;  // K / 32
  for (int t = 0; t < nt; ++t) {
    const int slot = t & 3, s3 = (t + 3) & 3;
    const int kt3 = (t + 3 < nt) ? (t + 3) : (t + 3 - nt);  // wrap keeps ledger uniform
    f16x8 af[8], bf[4];

    // ---- P1: mi 0-3 ----
    STG_A(s3, kt3)
    #pragma unroll
    for (int i2 = 0; i2 < 4; ++i2) af[i2] = *(const f16x8*)&sA[slot][aoff + i2 * 512];
    #pragma unroll
    for (int j = 0; j < 4; ++j) bf[j] = *(const f16x8*)&sB[slot][boff + j * 512];
    LGKM0; SCHED0;
    __builtin_amdgcn_s_setprio(1);
    #pragma unroll
    for (int i2 = 0; i2 < 4; ++i2)
      #pragma unroll
      for (int j = 0; j < 4; ++j)
        acc[i2][j] = MFMA16(af[i2], bf[j], acc[i2][j]);
    __builtin_amdgcn_s_setprio(0);

    // ---- P2: mi 4-7 ----
    STG_B(s3, kt3)
    #pragma unroll
    for (int i2 = 0; i2 < 4; ++i2) af[i2 + 4] = *(const f16x8*)&sA[slot][aoff + (i2 + 4) * 512];
    LGKM0; SCHED0;
    __builtin_amdgcn_s_setprio(1);
    #pragma unroll
    for (int i2 = 0; i2 < 4; ++i2)
      #pragma unroll
      for (int j = 0; j < 4; ++j)
        acc[i2 + 4][j] = MFMA16(af[i2 + 4], bf[j], acc[i2 + 4][j]);
    __builtin_amdgcn_s_setprio(0);

    VM8;   // retires tile t+1's 4 loads (leaves t+2, t+3 in flight)
    BAR;   // publishes tile t+1; proves slot (t+3)%4 readable for restage
  }
  VM0;  // drain wrap stages

  // epilogue: head = bm>>3 (blocks never straddle heads); plain f32 stores
  const int head = bm >> 3;
  const long coff = (long)head * 32000;
  const int row0 = (bm & 7) * 256 + wm * 128 + lk * 4;
  const int col0 = bn * 256 + wn * 64 + lr;
  #pragma unroll
  for (int mi = 0; mi < 8; ++mi) {
    #pragma unroll
    for (int ni = 0; ni < 4; ++ni) {
      int col = col0 + ni * 16;
      #pragma unroll
      for (int rg = 0; rg < 4; ++rg) {
        int row = row0 + mi * 16 + rg;
        if (row < MROWS) C[(long)row * 96000 + coff + col] = acc[mi][ni][rg];
      }
    }
  }
#undef STG_A
#undef STG_B
}

// ---------------- host-side orchestration ----------------
extern "C" void kernel_launch(void* const* d_in, const int* in_sizes, int n_in,
                              void* d_out, int out_size, void* d_ws, size_t ws_size,
                              hipStream_t stream) {
  const int*   tok   = (const int*)d_in[0];
  const float* embed = (const float*)d_in[1];
  auto P = [&](int k, int j) { return (const float*)d_in[2 + k * 14 + j]; };
  float* out = (float*)d_out;

  char* w = (char*)d_ws;
  auto alloc = [&](size_t bytes) { char* p = w; w += bytes; return p; };
  const size_t MM = (size_t)1024 * 1024;

  f16* embed_h = (f16*)alloc((size_t)32000 * 1024 * 2);
  f16* Wo_all  = (f16*)alloc(3 * MM * 2);
  f16* Wvo_all = (f16*)alloc(3 * MM * 2);
  f16 *Wm_h[3], *W1_h[3], *W2_h[3];
  for (int k = 0; k < 3; ++k) {
    Wm_h[k]  = (f16*)alloc((size_t)1024 * 2048 * 2);
    W1_h[k]  = (f16*)alloc((size_t)2048 * 1024 * 2);
    W2_h[k]  = (f16*)alloc((size_t)1024 * 2048 * 2);
  }
  float* hprev  = (float*)alloc((size_t)MPAD * 1024 * 4);
  f16*   h_all  = (f16*)alloc((size_t)3 * MPAD * 1024 * 2);
  f16*   merged = (f16*)alloc((size_t)MPAD * 2048 * 2);
  float* xf     = (float*)alloc((size_t)MPAD * 1024 * 4);
  f16*   xh     = (f16*)alloc((size_t)MPAD * 1024 * 2);
  f16*   ff1    = (f16*)alloc((size_t)MPAD * 2048 * 2);
  float* t1     = (float*)alloc((size_t)MPAD * 1024 * 4);
  float* bvo    = (float*)alloc(3 * 1024 * 4);
  f16* WvT_all = merged;  // scratch overlay (merged written later, stream-ordered)

  // ---- prep ----
  conv_f32_f16<<<16000, 256, 0, stream>>>(embed, embed_h, (long)32000 * 1024);

  ConvArgs ca;
  for (int k = 0; k < 3; ++k) {
    ca.s[k*4+0] = P(k, 0); ca.d[k*4+0] = Wm_h[k];        ca.n[k*4+0] = (long)1024 * 2048;
    ca.s[k*4+1] = P(k, 4); ca.d[k*4+1] = Wo_all + k*MM;  ca.n[k*4+1] = (long)1024 * 1024;
    ca.s[k*4+2] = P(k, 6); ca.d[k*4+2] = W1_h[k];        ca.n[k*4+2] = (long)2048 * 1024;
    ca.s[k*4+3] = P(k, 8); ca.d[k*4+3] = W2_h[k];        ca.n[k*4+3] = (long)1024 * 2048;
  }
  conv_many<<<dim3(1024, 12), 256, 0, stream>>>(ca);

  TpArgs ta;
  for (int k = 0; k < 3; ++k) { ta.s[k] = P(k, 2); ta.d[k] = WvT_all + k * MM; }
  transpose3<<<dim3(32, 32, 3), 256, 0, stream>>>(ta);

  gemm_sm<0, 0, 0, 1, 0><<<dim3(16, 16, 3), 256, 0, stream>>>(
      Wo_all, WvT_all, nullptr, nullptr, Wvo_all, 1024, 1024, 1024L, 0L, 1024,
      (long)MM, (long)MM, (long)MM);

  BvoArgs ba;
  for (int k = 0; k < 3; ++k) {
    ba.Wo[k] = P(k, 4); ba.bv[k] = P(k, 3); ba.bo[k] = P(k, 5); ba.out[k] = bvo + k * 1024;
  }
  make_bvo3<<<dim3(1024, 3), 64, 0, stream>>>(ba);

  // ---- 3 encoder chains (logits deferred to one mega GEMM) ----
  for (int k = 0; k < 3; ++k) {
    merge_rms<<<MROWS, 256, 0, stream>>>(hprev, embed, tok, merged, k + 1,
                                         k == 0 ? 0 : -1);
    gemm_sm<1, 0, 1, 1, 0><<<dim3(16, 32), 256, 0, stream>>>(
        merged, Wm_h[k], P(k, 1), xf, xh, 2048, 1024, 1024L, 0L, MROWS, 0L, 0L, 0L);
    gemm_sm<1, 0, 1, 0, 0><<<dim3(16, 32), 256, 0, stream>>>(
        xh, Wvo_all + k * MM, bvo + k * 1024, t1, nullptr, 1024, 1024, 1024L, 0L,
        MROWS, 0L, 0L, 0L);
    add_ln<<<MROWS, 256, 0, stream>>>(xf, t1, P(k, 10), P(k, 11), xf, xh);
    gemm_sm<1, 1, 0, 1, 0><<<dim3(32, 32), 256, 0, stream>>>(
        xh, W1_h[k], P(k, 7), nullptr, ff1, 1024, 2048, 2048L, 0L, MROWS, 0L, 0L, 0L);
    gemm_sm<1, 0, 1, 0, 0><<<dim3(16, 32), 256, 0, stream>>>(
        ff1, W2_h[k], P(k, 9), t1, nullptr, 2048, 1024, 1024L, 0L, MROWS, 0L, 0L, 0L);
    add_ln<<<MROWS, 256, 0, stream>>>(xf, t1, P(k, 12), P(k, 13), hprev,
                                      h_all + (size_t)k * MPAD * 1024);
  }

  // ---- one mega logits GEMM (deep-ring) ----
  gemm256x<<<dim3(125, 24), 512, 0, stream>>>(h_all, embed_h, out);
}